// Round 5
// baseline (413.794 us; speedup 1.0000x reference)
//
#include <hip/hip_runtime.h>

typedef unsigned short u16;
typedef __attribute__((ext_vector_type(8))) short bf16x8;
typedef __attribute__((ext_vector_type(4))) short bf16x4;
typedef __attribute__((ext_vector_type(4))) float f32x4;

#define MFMA16(a, b, c) __builtin_amdgcn_mfma_f32_16x16x32_bf16(a, b, c, 0, 0, 0)

__device__ __forceinline__ u16 f2bf(float x) {
    unsigned u = __float_as_uint(x);
    return (u16)((u + 0x7fffu + ((u >> 16) & 1u)) >> 16);
}
__device__ __forceinline__ u16 f2bf_fast(float x) {  // round-half-up (P matrix only)
    return (u16)((__float_as_uint(x) + 0x8000u) >> 16);
}

// ---------------------------------------------------------------------------
// fp32 -> bf16 flat cast. n must be a multiple of 8*256.
// ---------------------------------------------------------------------------
__global__ __launch_bounds__(256) void castk(const float* __restrict__ src, u16* __restrict__ dst) {
    const int i = (blockIdx.x * 256 + threadIdx.x) * 8;
    float4 a = *(const float4*)(src + i);
    float4 b = *(const float4*)(src + i + 4);
    bf16x8 v;
    v[0] = (short)f2bf(a.x); v[1] = (short)f2bf(a.y);
    v[2] = (short)f2bf(a.z); v[3] = (short)f2bf(a.w);
    v[4] = (short)f2bf(b.x); v[5] = (short)f2bf(b.y);
    v[6] = (short)f2bf(b.z); v[7] = (short)f2bf(b.w);
    *(bf16x8*)(dst + i) = v;
}

// ---------------------------------------------------------------------------
// fp32 src[r][c] -> bf16 dst[c][r], 64x64 LDS tiles. grid R/64*C/64, block 256
// ---------------------------------------------------------------------------
__global__ __launch_bounds__(256) void tkern(const float* __restrict__ src, u16* __restrict__ dst,
                                             int R, int C) {
    const int tC = C >> 6;
    const int tr = (blockIdx.x / tC) << 6;
    const int tc = (blockIdx.x % tC) << 6;
    __shared__ u16 ls[64 * 68];
    const int tid = threadIdx.x;
#pragma unroll
    for (int rep = 0; rep < 2; ++rep) {
        const int f = tid * 8 + rep * 2048;
        const int r = f >> 6, c = f & 63;
        float4 a = *(const float4*)(src + (size_t)(tr + r) * C + tc + c);
        float4 b = *(const float4*)(src + (size_t)(tr + r) * C + tc + c + 4);
        bf16x4 lo, hi;
        lo[0] = (short)f2bf(a.x); lo[1] = (short)f2bf(a.y);
        lo[2] = (short)f2bf(a.z); lo[3] = (short)f2bf(a.w);
        hi[0] = (short)f2bf(b.x); hi[1] = (short)f2bf(b.y);
        hi[2] = (short)f2bf(b.z); hi[3] = (short)f2bf(b.w);
        *(bf16x4*)&ls[r * 68 + c] = lo;
        *(bf16x4*)&ls[r * 68 + c + 4] = hi;
    }
    __syncthreads();
#pragma unroll
    for (int rep = 0; rep < 2; ++rep) {
        const int f = tid * 8 + rep * 2048;
        const int rn = f >> 6, ck = f & 63;
        bf16x8 v;
#pragma unroll
        for (int j = 0; j < 8; ++j) v[j] = (short)ls[(ck + j) * 68 + rn];
        *(bf16x8*)(dst + (size_t)(tc + rn) * R + tr + ck) = v;
    }
}

// ---------------------------------------------------------------------------
// GEMM: C[m][n] = sum_k A[m][k] * Bt[n][k] + bias[n].  M=8192, K=1024, bf16.
// MODE 0: N=3072, scatter to Q(scaled)[BH][T][D], K[BH][T][D], V^T[BH][D][T].
// MODE 1: N=1024, fp32 store to Of[M][N].
// ---------------------------------------------------------------------------
template <int MODE>
__global__ __launch_bounds__(256) void gemm_k(const u16* __restrict__ A, const u16* __restrict__ Bt,
                                              const float* __restrict__ bias,
                                              u16* __restrict__ Qo, u16* __restrict__ Ko,
                                              u16* __restrict__ Vo, float* __restrict__ Of) {
    constexpr int Kd = 1024;
    const int tid = threadIdx.x;
    const int lane = tid & 63, wave = tid >> 6;
    const int wm = wave >> 1, wn = wave & 1;
    const int lr = lane & 15, lg = lane >> 4;
    const int mt = blockIdx.x & 63;
    const int nt = blockIdx.x >> 6;
    const int mbase = mt << 7, nbase = nt << 7;
    __shared__ u16 As[128 * 32];
    __shared__ u16 Bs[128 * 32];
    f32x4 acc[4][4];
#pragma unroll
    for (int i = 0; i < 4; ++i)
#pragma unroll
        for (int j = 0; j < 4; ++j) acc[i][j] = {0.f, 0.f, 0.f, 0.f};

    for (int kb = 0; kb < Kd; kb += 32) {
        __syncthreads();
#pragma unroll
        for (int rep = 0; rep < 2; ++rep) {
            const int f = tid * 8 + rep * 2048;
            const int r = f >> 5, c = f & 31;
            __builtin_amdgcn_global_load_lds(
                (const __attribute__((address_space(1))) void*)(A + (size_t)(mbase + r) * Kd + kb + c),
                (__attribute__((address_space(3))) void*)(As + f), 16, 0, 0);
            __builtin_amdgcn_global_load_lds(
                (const __attribute__((address_space(1))) void*)(Bt + (size_t)(nbase + r) * Kd + kb + c),
                (__attribute__((address_space(3))) void*)(Bs + f), 16, 0, 0);
        }
        __syncthreads();
        bf16x8 af[4], bfr[4];
#pragma unroll
        for (int i = 0; i < 4; ++i)
            af[i] = *(const bf16x8*)&As[(wm * 64 + i * 16 + lr) * 32 + lg * 8];
#pragma unroll
        for (int j = 0; j < 4; ++j)
            bfr[j] = *(const bf16x8*)&Bs[(wn * 64 + j * 16 + lr) * 32 + lg * 8];
#pragma unroll
        for (int i = 0; i < 4; ++i)
#pragma unroll
            for (int j = 0; j < 4; ++j) acc[i][j] = MFMA16(af[i], bfr[j], acc[i][j]);
    }

    const float QSCALE = 0.1803368801111137f;  // 0.125 * log2(e), folded into Q
#pragma unroll
    for (int j = 0; j < 4; ++j) {
        const int n = nbase + wn * 64 + j * 16 + lr;
        const float bj = bias[n];
        if (MODE == 0) {
            const int three = n >> 10;
            const int h = (n >> 6) & 15;
            const int d = n & 63;
#pragma unroll
            for (int i = 0; i < 4; ++i) {
#pragma unroll
                for (int r = 0; r < 4; ++r) {
                    const int m = mbase + wm * 64 + i * 16 + lg * 4 + r;
                    const int b = m >> 11, t = m & 2047;
                    const int bh = (b << 4) + h;
                    const float val = acc[i][j][r] + bj;
                    if (three == 0)
                        Qo[(((size_t)bh << 11) + t) * 64 + d] = f2bf(val * QSCALE);
                    else if (three == 1)
                        Ko[(((size_t)bh << 11) + t) * 64 + d] = f2bf(val);
                    else
                        Vo[(((size_t)bh << 6) + d) * 2048 + t] = f2bf(val);
                }
            }
        } else {
#pragma unroll
            for (int i = 0; i < 4; ++i) {
#pragma unroll
                for (int r = 0; r < 4; ++r) {
                    const int m = mbase + wm * 64 + i * 16 + lg * 4 + r;
                    Of[((size_t)m << 10) + n] = acc[i][j][r] + bj;
                }
            }
        }
    }
}

// ---------------------------------------------------------------------------
// Causal flash attention, barrier-free, register K/V frags, O^T accumulation,
// cross-iteration K-fragment double-buffer (register prefetch).
// Q,K: [BH][T][D] bf16 (Q pre-scaled), Vt: [BH][D][T] bf16, Aout: [B][T][C].
// grid (16, B*H), block 128 (2 waves). Block bx pairs q-tiles qb_hi=16+bx,
// qb_lo=15-bx (perfect balance). O^T trick: PV computes O^T = V^T x P^T via
// the SAME pf/vf registers (operand swap) -> alpha & 1/l become lane-uniform
// (q = lr = C-layout column): no shuffles in the softmax rescale/epilogue.
// ---------------------------------------------------------------------------
__global__ __launch_bounds__(128, 2) void flash_attn(const u16* __restrict__ Q, const u16* __restrict__ Kg,
                                                     const u16* __restrict__ Vt, u16* __restrict__ Aout) {
    const int tid = threadIdx.x;
    const int lane = tid & 63, wave = tid >> 6;  // wave 0..1
    const int lr = lane & 15, lg = lane >> 4;
    const int bx = blockIdx.x;   // 0..15
    const int bh = blockIdx.y;   // 0..63
    const int b = bh >> 4, h = bh & 15;
    const size_t base = (size_t)bh << 17;  // bh * 2048 * 64

    const int qb_hi = 16 + bx;
    const int qb_lo = 15 - bx;

    __shared__ u16 Ps[2][16 * 72];  // per-wave P scratch

    // subtile q-bases: 0,1 = hi halves; 2,3 = lo halves
    int qbase[4];
    qbase[0] = qb_hi * 64 + wave * 32;
    qbase[1] = qbase[0] + 16;
    qbase[2] = qb_lo * 64 + wave * 32;
    qbase[3] = qbase[2] + 16;

    bf16x8 qf[4][2];
#pragma unroll
    for (int st = 0; st < 4; ++st) {
        const u16* p = Q + base + (size_t)(qbase[st] + lr) * 64;
        qf[st][0] = *(const bf16x8*)(p + lg * 8);
        qf[st][1] = *(const bf16x8*)(p + 32 + lg * 8);
    }

    f32x4 o[4][4];  // O^T: per (st,dt) tile, col=lr=q, row=lg*4+r=d
#pragma unroll
    for (int st = 0; st < 4; ++st)
#pragma unroll
        for (int dt = 0; dt < 4; ++dt) o[st][dt] = {0.f, 0.f, 0.f, 0.f};
    float m_[4] = {-INFINITY, -INFINITY, -INFINITY, -INFINITY};
    float l_[4] = {0.f, 0.f, 0.f, 0.f};

    const u16* Kbase = Kg + base + (size_t)lr * 64 + lg * 8;
    const u16* Vbase = Vt + base + (size_t)lr * 2048 + lg * 8;

    auto loadK = [&](int kt, bf16x8 (&kf)[4][2]) {
        const u16* kp = Kbase + (size_t)kt * 4096;
#pragma unroll
        for (int rt = 0; rt < 4; ++rt) {
            kf[rt][0] = *(const bf16x8*)(kp + rt * 1024);
            kf[rt][1] = *(const bf16x8*)(kp + rt * 1024 + 32);
        }
    };

    bf16x8 kfA[4][2], kfB[4][2];
    loadK(0, kfA);

    // one kt iteration: prefetch next K frags into kfN, V frags single-buffered
    auto iter = [&](int kt, bf16x8 (&kf)[4][2], bf16x8 (&kfN)[4][2]) {
        loadK(kt < qb_hi ? kt + 1 : qb_hi, kfN);  // in-flight during compute
        bf16x8 vf[4][2];
        const u16* vp = Vbase + kt * 64;
#pragma unroll
        for (int dt = 0; dt < 4; ++dt) {
            vf[dt][0] = *(const bf16x8*)(vp + dt * 32768);
            vf[dt][1] = *(const bf16x8*)(vp + dt * 32768 + 32);
        }

        auto process = [&](int st, bool diag) {
            // S^T[kv][q]: C-layout q=lr, kv = kt*64 + rt*16 + lg*4 + reg
            f32x4 s[4];
#pragma unroll
            for (int rt = 0; rt < 4; ++rt) {
                f32x4 z = {0.f, 0.f, 0.f, 0.f};
                z = MFMA16(kf[rt][0], qf[st][0], z);
                z = MFMA16(kf[rt][1], qf[st][1], z);
                s[rt] = z;
            }
            if (diag) {
                const int q_glob = qbase[st] + lr;
#pragma unroll
                for (int rt = 0; rt < 4; ++rt)
#pragma unroll
                    for (int r = 0; r < 4; ++r) {
                        const int kv = kt * 64 + rt * 16 + lg * 4 + r;
                        if (kv > q_glob) s[rt][r] = -INFINITY;
                    }
            }
            float rmax = -INFINITY;
#pragma unroll
            for (int rt = 0; rt < 4; ++rt)
#pragma unroll
                for (int r = 0; r < 4; ++r) rmax = fmaxf(rmax, s[rt][r]);
            rmax = fmaxf(rmax, __shfl_xor(rmax, 16));
            rmax = fmaxf(rmax, __shfl_xor(rmax, 32));
            const float m_new = fmaxf(m_[st], rmax);
            const float alpha = exp2f(m_[st] - m_new);  // per-lane (q=lr) uniform
            float rsum = 0.f;
#pragma unroll
            for (int rt = 0; rt < 4; ++rt)
#pragma unroll
                for (int r = 0; r < 4; ++r) {
                    const float p = exp2f(s[rt][r] - m_new);
                    s[rt][r] = p;
                    rsum += p;
                }
            rsum += __shfl_xor(rsum, 16);
            rsum += __shfl_xor(rsum, 32);
            l_[st] = l_[st] * alpha + rsum;
            m_[st] = m_new;

            // P (C-layout) -> LDS -> A/B fragment layout
#pragma unroll
            for (int rt = 0; rt < 4; ++rt) {
                bf16x4 pk;
#pragma unroll
                for (int r = 0; r < 4; ++r) pk[r] = (short)f2bf_fast(s[rt][r]);
                *(bf16x4*)&Ps[wave][lr * 72 + rt * 16 + lg * 4] = pk;
            }
            if (__any(alpha != 1.0f)) {
#pragma unroll
                for (int dt = 0; dt < 4; ++dt)
#pragma unroll
                    for (int r = 0; r < 4; ++r) o[st][dt][r] *= alpha;
            }
            const bf16x8 pf0 = *(const bf16x8*)&Ps[wave][lr * 72 + lg * 8];
            const bf16x8 pf1 = *(const bf16x8*)&Ps[wave][lr * 72 + 32 + lg * 8];
            // O^T += V^T x P^T : A = vf, B = pf (same registers, swapped roles)
#pragma unroll
            for (int dt = 0; dt < 4; ++dt) {
                o[st][dt] = MFMA16(vf[dt][0], pf0, o[st][dt]);
                o[st][dt] = MFMA16(vf[dt][1], pf1, o[st][dt]);
            }
        };

        process(0, kt == qb_hi);
        process(1, kt == qb_hi);
        if (kt <= qb_lo) {
            process(2, kt == qb_lo);
            process(3, kt == qb_lo);
        }
    };

    for (int kt = 0; kt <= qb_hi;) {
        iter(kt, kfA, kfB);
        ++kt;
        if (kt > qb_hi) break;
        iter(kt, kfB, kfA);
        ++kt;
    }

    // epilogue: O^T store, linv lane-uniform, bf16x4 per (st,dt)
#pragma unroll
    for (int st = 0; st < 4; ++st) {
        const float linv = 1.f / l_[st];
        const int t = qbase[st] + lr;
#pragma unroll
        for (int dt = 0; dt < 4; ++dt) {
            bf16x4 pk;
#pragma unroll
            for (int r = 0; r < 4; ++r) pk[r] = (short)f2bf(o[st][dt][r] * linv);
            *(bf16x4*)&Aout[(((size_t)(b << 11) + t) << 10) + h * 64 + dt * 16 + lg * 4] = pk;
        }
    }
}

// ---------------------------------------------------------------------------
extern "C" void kernel_launch(void* const* d_in, const int* in_sizes, int n_in,
                              void* d_out, int out_size, void* d_ws, size_t ws_size,
                              hipStream_t stream) {
    (void)in_sizes; (void)n_in; (void)out_size; (void)ws_size;
    const float* x    = (const float*)d_in[0];
    const float* Wqkv = (const float*)d_in[2];
    const float* bqkv = (const float*)d_in[3];
    const float* Wout = (const float*)d_in[4];
    const float* bout = (const float*)d_in[5];
    float* out = (float*)d_out;

    char* ws = (char*)d_ws;
    u16* WqkvT = (u16*)(ws);                    //  6 MB: [3072][1024] bf16
    u16* WoutT = (u16*)(ws + 6291456);          //  2 MB: [1024][1024] bf16
    u16* xb    = (u16*)(ws + 8388608);          // 16 MB: [8192][1024] bf16
    u16* Qb    = (u16*)(ws + 25165824);         // 16 MB: [BH][T][D]
    u16* Kb    = (u16*)(ws + 41943040);         // 16 MB: [BH][T][D]
    u16* Vtb   = (u16*)(ws + 58720256);         // 16 MB: [BH][D][T]
    u16* Ab    = (u16*)(ws + 75497472);         // 16 MB: [B][T][C]

    castk<<<dim3(4096), 256, 0, stream>>>(x, xb);
    tkern<<<dim3(16 * 48), 256, 0, stream>>>(Wqkv, WqkvT, 1024, 3072);
    tkern<<<dim3(16 * 16), 256, 0, stream>>>(Wout, WoutT, 1024, 1024);
    gemm_k<0><<<dim3(64 * 24), 256, 0, stream>>>(xb, WqkvT, bqkv, Qb, Kb, Vtb, nullptr);
    flash_attn<<<dim3(16, 64), 128, 0, stream>>>(Qb, Kb, Vtb, Ab);
    gemm_k<1><<<dim3(64 * 8), 256, 0, stream>>>(Ab, WoutT, bout, nullptr, nullptr, nullptr, out);
}

// Round 6
// 339.176 us; speedup vs baseline: 1.2200x; 1.2200x over previous
//
#include <hip/hip_runtime.h>

typedef unsigned short u16;
typedef __attribute__((ext_vector_type(8))) short bf16x8;
typedef __attribute__((ext_vector_type(4))) short bf16x4;
typedef __attribute__((ext_vector_type(4))) float f32x4;

#define MFMA16(a, b, c) __builtin_amdgcn_mfma_f32_16x16x32_bf16(a, b, c, 0, 0, 0)

__device__ __forceinline__ u16 f2bf(float x) {
    unsigned u = __float_as_uint(x);
    return (u16)((u + 0x7fffu + ((u >> 16) & 1u)) >> 16);
}
__device__ __forceinline__ u16 f2bf_fast(float x) {  // round-half-up (P matrix only)
    return (u16)((__float_as_uint(x) + 0x8000u) >> 16);
}

// ---------------------------------------------------------------------------
// fp32 -> bf16 flat cast. n must be a multiple of 8*256.
// ---------------------------------------------------------------------------
__global__ __launch_bounds__(256) void castk(const float* __restrict__ src, u16* __restrict__ dst) {
    const int i = (blockIdx.x * 256 + threadIdx.x) * 8;
    float4 a = *(const float4*)(src + i);
    float4 b = *(const float4*)(src + i + 4);
    bf16x8 v;
    v[0] = (short)f2bf(a.x); v[1] = (short)f2bf(a.y);
    v[2] = (short)f2bf(a.z); v[3] = (short)f2bf(a.w);
    v[4] = (short)f2bf(b.x); v[5] = (short)f2bf(b.y);
    v[6] = (short)f2bf(b.z); v[7] = (short)f2bf(b.w);
    *(bf16x8*)(dst + i) = v;
}

// ---------------------------------------------------------------------------
// fp32 src[r][c] -> bf16 dst[c][r], 64x64 LDS tiles. grid R/64*C/64, block 256
// ---------------------------------------------------------------------------
__global__ __launch_bounds__(256) void tkern(const float* __restrict__ src, u16* __restrict__ dst,
                                             int R, int C) {
    const int tC = C >> 6;
    const int tr = (blockIdx.x / tC) << 6;
    const int tc = (blockIdx.x % tC) << 6;
    __shared__ u16 ls[64 * 68];
    const int tid = threadIdx.x;
#pragma unroll
    for (int rep = 0; rep < 2; ++rep) {
        const int f = tid * 8 + rep * 2048;
        const int r = f >> 6, c = f & 63;
        float4 a = *(const float4*)(src + (size_t)(tr + r) * C + tc + c);
        float4 b = *(const float4*)(src + (size_t)(tr + r) * C + tc + c + 4);
        bf16x4 lo, hi;
        lo[0] = (short)f2bf(a.x); lo[1] = (short)f2bf(a.y);
        lo[2] = (short)f2bf(a.z); lo[3] = (short)f2bf(a.w);
        hi[0] = (short)f2bf(b.x); hi[1] = (short)f2bf(b.y);
        hi[2] = (short)f2bf(b.z); hi[3] = (short)f2bf(b.w);
        *(bf16x4*)&ls[r * 68 + c] = lo;
        *(bf16x4*)&ls[r * 68 + c + 4] = hi;
    }
    __syncthreads();
#pragma unroll
    for (int rep = 0; rep < 2; ++rep) {
        const int f = tid * 8 + rep * 2048;
        const int rn = f >> 6, ck = f & 63;
        bf16x8 v;
#pragma unroll
        for (int j = 0; j < 8; ++j) v[j] = (short)ls[(ck + j) * 68 + rn];
        *(bf16x8*)(dst + (size_t)(tc + rn) * R + tr + ck) = v;
    }
}

// ---------------------------------------------------------------------------
// GEMM: C[m][n] = sum_k A[m][k] * Bt[n][k] + bias[n].  M=8192, K=1024, bf16.
// MODE 0: N=3072, scatter to Q(scaled)[BH][T][D], K[BH][T][D], V^T[BH][D][T].
// MODE 1: N=1024, fp32 store to Of[M][N].
// ---------------------------------------------------------------------------
template <int MODE>
__global__ __launch_bounds__(256) void gemm_k(const u16* __restrict__ A, const u16* __restrict__ Bt,
                                              const float* __restrict__ bias,
                                              u16* __restrict__ Qo, u16* __restrict__ Ko,
                                              u16* __restrict__ Vo, float* __restrict__ Of) {
    constexpr int Kd = 1024;
    const int tid = threadIdx.x;
    const int lane = tid & 63, wave = tid >> 6;
    const int wm = wave >> 1, wn = wave & 1;
    const int lr = lane & 15, lg = lane >> 4;
    const int mt = blockIdx.x & 63;
    const int nt = blockIdx.x >> 6;
    const int mbase = mt << 7, nbase = nt << 7;
    __shared__ u16 As[128 * 32];
    __shared__ u16 Bs[128 * 32];
    f32x4 acc[4][4];
#pragma unroll
    for (int i = 0; i < 4; ++i)
#pragma unroll
        for (int j = 0; j < 4; ++j) acc[i][j] = {0.f, 0.f, 0.f, 0.f};

    for (int kb = 0; kb < Kd; kb += 32) {
        __syncthreads();
#pragma unroll
        for (int rep = 0; rep < 2; ++rep) {
            const int f = tid * 8 + rep * 2048;
            const int r = f >> 5, c = f & 31;
            __builtin_amdgcn_global_load_lds(
                (const __attribute__((address_space(1))) void*)(A + (size_t)(mbase + r) * Kd + kb + c),
                (__attribute__((address_space(3))) void*)(As + f), 16, 0, 0);
            __builtin_amdgcn_global_load_lds(
                (const __attribute__((address_space(1))) void*)(Bt + (size_t)(nbase + r) * Kd + kb + c),
                (__attribute__((address_space(3))) void*)(Bs + f), 16, 0, 0);
        }
        __syncthreads();
        bf16x8 af[4], bfr[4];
#pragma unroll
        for (int i = 0; i < 4; ++i)
            af[i] = *(const bf16x8*)&As[(wm * 64 + i * 16 + lr) * 32 + lg * 8];
#pragma unroll
        for (int j = 0; j < 4; ++j)
            bfr[j] = *(const bf16x8*)&Bs[(wn * 64 + j * 16 + lr) * 32 + lg * 8];
#pragma unroll
        for (int i = 0; i < 4; ++i)
#pragma unroll
            for (int j = 0; j < 4; ++j) acc[i][j] = MFMA16(af[i], bfr[j], acc[i][j]);
    }

    const float QSCALE = 0.1803368801111137f;  // 0.125 * log2(e), folded into Q
#pragma unroll
    for (int j = 0; j < 4; ++j) {
        const int n = nbase + wn * 64 + j * 16 + lr;
        const float bj = bias[n];
        if (MODE == 0) {
            const int three = n >> 10;
            const int h = (n >> 6) & 15;
            const int d = n & 63;
#pragma unroll
            for (int i = 0; i < 4; ++i) {
#pragma unroll
                for (int r = 0; r < 4; ++r) {
                    const int m = mbase + wm * 64 + i * 16 + lg * 4 + r;
                    const int b = m >> 11, t = m & 2047;
                    const int bh = (b << 4) + h;
                    const float val = acc[i][j][r] + bj;
                    if (three == 0)
                        Qo[(((size_t)bh << 11) + t) * 64 + d] = f2bf(val * QSCALE);
                    else if (three == 1)
                        Ko[(((size_t)bh << 11) + t) * 64 + d] = f2bf(val);
                    else
                        Vo[(((size_t)bh << 6) + d) * 2048 + t] = f2bf(val);
                }
            }
        } else {
#pragma unroll
            for (int i = 0; i < 4; ++i) {
#pragma unroll
                for (int r = 0; r < 4; ++r) {
                    const int m = mbase + wm * 64 + i * 16 + lg * 4 + r;
                    Of[((size_t)m << 10) + n] = acc[i][j][r] + bj;
                }
            }
        }
    }
}

// ---------------------------------------------------------------------------
// Flash attention helpers — forceinline, plain reference params (no lambdas
// in the hot path: R5's lambda-held fragment buffers got homed to scratch ->
// 280 MB of spill writes; explicit locals + forceinline keep them in VGPRs).
// ---------------------------------------------------------------------------
__device__ __forceinline__ void fa_loadK(const u16* __restrict__ Kbase, int kt, bf16x8 (&kf)[4][2]) {
    const u16* kp = Kbase + (size_t)kt * 4096;
#pragma unroll
    for (int rt = 0; rt < 4; ++rt) {
        kf[rt][0] = *(const bf16x8*)(kp + rt * 1024);
        kf[rt][1] = *(const bf16x8*)(kp + rt * 1024 + 32);
    }
}

__device__ __forceinline__ void fa_process(
    int lane, int lr, int lg, int kt, int qbase_st, bool diag,
    const bf16x8 (&kf)[4][2], const bf16x8 (&vf)[4][2],
    const bf16x8& qf0, const bf16x8& qf1,
    f32x4 (&o)[4], float& m_i, float& l_i, u16* __restrict__ Psw) {
    // S^T[kv][q]: C-layout q=lr (column), kv = kt*64 + rt*16 + lg*4 + reg
    f32x4 s[4];
#pragma unroll
    for (int rt = 0; rt < 4; ++rt) {
        f32x4 z = {0.f, 0.f, 0.f, 0.f};
        z = MFMA16(kf[rt][0], qf0, z);
        z = MFMA16(kf[rt][1], qf1, z);
        s[rt] = z;
    }
    if (diag) {
        const int q_glob = qbase_st + lr;
#pragma unroll
        for (int rt = 0; rt < 4; ++rt)
#pragma unroll
            for (int r = 0; r < 4; ++r) {
                const int kv = kt * 64 + rt * 16 + lg * 4 + r;
                if (kv > q_glob) s[rt][r] = -INFINITY;
            }
    }
    float rmax = -INFINITY;
#pragma unroll
    for (int rt = 0; rt < 4; ++rt)
#pragma unroll
        for (int r = 0; r < 4; ++r) rmax = fmaxf(rmax, s[rt][r]);
    rmax = fmaxf(rmax, __shfl_xor(rmax, 16));
    rmax = fmaxf(rmax, __shfl_xor(rmax, 32));
    const float m_new = fmaxf(m_i, rmax);
    const float alpha = exp2f(m_i - m_new);  // lane-uniform in q (q = lr)
    float rsum = 0.f;
#pragma unroll
    for (int rt = 0; rt < 4; ++rt)
#pragma unroll
        for (int r = 0; r < 4; ++r) {
            const float p = exp2f(s[rt][r] - m_new);
            s[rt][r] = p;
            rsum += p;
        }
    rsum += __shfl_xor(rsum, 16);
    rsum += __shfl_xor(rsum, 32);
    l_i = l_i * alpha + rsum;
    m_i = m_new;

    // P (C-layout) -> LDS -> fragment layout
#pragma unroll
    for (int rt = 0; rt < 4; ++rt) {
        bf16x4 pk;
#pragma unroll
        for (int r = 0; r < 4; ++r) pk[r] = (short)f2bf_fast(s[rt][r]);
        *(bf16x4*)&Psw[lr * 72 + rt * 16 + lg * 4] = pk;
    }
    if (__any(alpha != 1.0f)) {
#pragma unroll
        for (int dt = 0; dt < 4; ++dt)
#pragma unroll
            for (int r = 0; r < 4; ++r) o[dt][r] *= alpha;
    }
    const bf16x8 pf0 = *(const bf16x8*)&Psw[lr * 72 + lg * 8];
    const bf16x8 pf1 = *(const bf16x8*)&Psw[lr * 72 + 32 + lg * 8];
    // O^T += V^T x P^T (operand swap; O^T C-layout: col=lr=q, row=d)
#pragma unroll
    for (int dt = 0; dt < 4; ++dt) {
        o[dt] = MFMA16(vf[dt][0], pf0, o[dt]);
        o[dt] = MFMA16(vf[dt][1], pf1, o[dt]);
    }
}

// ---------------------------------------------------------------------------
// Causal flash attention: barrier-free, register K/V frags, O^T accumulation,
// explicit two-buffer K prefetch (kfE/kfO named locals, unroll-by-2 loop).
// grid (16, B*H), block 128 (2 waves). Block bx pairs q-tiles qb_hi=16+bx,
// qb_lo=15-bx (perfect balance); each wave owns 4 subtiles of 16 q.
// ---------------------------------------------------------------------------
__global__ __launch_bounds__(128, 2) void flash_attn(const u16* __restrict__ Q, const u16* __restrict__ Kg,
                                                     const u16* __restrict__ Vt, u16* __restrict__ Aout) {
    const int tid = threadIdx.x;
    const int lane = tid & 63, wave = tid >> 6;
    const int lr = lane & 15, lg = lane >> 4;
    const int bx = blockIdx.x;   // 0..15
    const int bh = blockIdx.y;   // 0..63
    const int b = bh >> 4, h = bh & 15;
    const size_t base = (size_t)bh << 17;

    const int qb_hi = 16 + bx;
    const int qb_lo = 15 - bx;

    __shared__ u16 Ps[2][16 * 72];
    u16* Psw = Ps[wave];

    int qbase[4];
    qbase[0] = qb_hi * 64 + wave * 32;
    qbase[1] = qbase[0] + 16;
    qbase[2] = qb_lo * 64 + wave * 32;
    qbase[3] = qbase[2] + 16;

    bf16x8 qf[4][2];
#pragma unroll
    for (int st = 0; st < 4; ++st) {
        const u16* p = Q + base + (size_t)(qbase[st] + lr) * 64;
        qf[st][0] = *(const bf16x8*)(p + lg * 8);
        qf[st][1] = *(const bf16x8*)(p + 32 + lg * 8);
    }

    f32x4 o[4][4];
#pragma unroll
    for (int st = 0; st < 4; ++st)
#pragma unroll
        for (int dt = 0; dt < 4; ++dt) o[st][dt] = {0.f, 0.f, 0.f, 0.f};
    float m_[4] = {-INFINITY, -INFINITY, -INFINITY, -INFINITY};
    float l_[4] = {0.f, 0.f, 0.f, 0.f};

    const u16* Kbase = Kg + base + (size_t)lr * 64 + lg * 8;
    const u16* Vbase = Vt + base + (size_t)lr * 2048 + lg * 8;

    bf16x8 kfE[4][2], kfO[4][2];
    fa_loadK(Kbase, 0, kfE);

    int kt = 0;
    while (true) {
        // even phase: consume kfE, prefetch kfO
        {
            fa_loadK(Kbase, kt < qb_hi ? kt + 1 : qb_hi, kfO);
            bf16x8 vf[4][2];
            const u16* vp = Vbase + kt * 64;
#pragma unroll
            for (int dt = 0; dt < 4; ++dt) {
                vf[dt][0] = *(const bf16x8*)(vp + dt * 32768);
                vf[dt][1] = *(const bf16x8*)(vp + dt * 32768 + 32);
            }
            const bool dg = (kt == qb_hi);
            fa_process(lane, lr, lg, kt, qbase[0], dg, kfE, vf, qf[0][0], qf[0][1], o[0], m_[0], l_[0], Psw);
            fa_process(lane, lr, lg, kt, qbase[1], dg, kfE, vf, qf[1][0], qf[1][1], o[1], m_[1], l_[1], Psw);
            if (kt <= qb_lo) {
                const bool dgl = (kt == qb_lo);
                fa_process(lane, lr, lg, kt, qbase[2], dgl, kfE, vf, qf[2][0], qf[2][1], o[2], m_[2], l_[2], Psw);
                fa_process(lane, lr, lg, kt, qbase[3], dgl, kfE, vf, qf[3][0], qf[3][1], o[3], m_[3], l_[3], Psw);
            }
        }
        if (++kt > qb_hi) break;
        // odd phase: consume kfO, prefetch kfE
        {
            fa_loadK(Kbase, kt < qb_hi ? kt + 1 : qb_hi, kfE);
            bf16x8 vf[4][2];
            const u16* vp = Vbase + kt * 64;
#pragma unroll
            for (int dt = 0; dt < 4; ++dt) {
                vf[dt][0] = *(const bf16x8*)(vp + dt * 32768);
                vf[dt][1] = *(const bf16x8*)(vp + dt * 32768 + 32);
            }
            const bool dg = (kt == qb_hi);
            fa_process(lane, lr, lg, kt, qbase[0], dg, kfO, vf, qf[0][0], qf[0][1], o[0], m_[0], l_[0], Psw);
            fa_process(lane, lr, lg, kt, qbase[1], dg, kfO, vf, qf[1][0], qf[1][1], o[1], m_[1], l_[1], Psw);
            if (kt <= qb_lo) {
                const bool dgl = (kt == qb_lo);
                fa_process(lane, lr, lg, kt, qbase[2], dgl, kfO, vf, qf[2][0], qf[2][1], o[2], m_[2], l_[2], Psw);
                fa_process(lane, lr, lg, kt, qbase[3], dgl, kfO, vf, qf[3][0], qf[3][1], o[3], m_[3], l_[3], Psw);
            }
        }
        if (++kt > qb_hi) break;
    }

    // epilogue: O^T store, linv lane-uniform, bf16x4 per (st,dt)
#pragma unroll
    for (int st = 0; st < 4; ++st) {
        const float linv = 1.f / l_[st];
        const int t = qbase[st] + lr;
#pragma unroll
        for (int dt = 0; dt < 4; ++dt) {
            bf16x4 pk;
#pragma unroll
            for (int r = 0; r < 4; ++r) pk[r] = (short)f2bf(o[st][dt][r] * linv);
            *(bf16x4*)&Aout[(((size_t)(b << 11) + t) << 10) + h * 64 + dt * 16 + lg * 4] = pk;
        }
    }
}

// ---------------------------------------------------------------------------
extern "C" void kernel_launch(void* const* d_in, const int* in_sizes, int n_in,
                              void* d_out, int out_size, void* d_ws, size_t ws_size,
                              hipStream_t stream) {
    (void)in_sizes; (void)n_in; (void)out_size; (void)ws_size;
    const float* x    = (const float*)d_in[0];
    const float* Wqkv = (const float*)d_in[2];
    const float* bqkv = (const float*)d_in[3];
    const float* Wout = (const float*)d_in[4];
    const float* bout = (const float*)d_in[5];
    float* out = (float*)d_out;

    char* ws = (char*)d_ws;
    u16* WqkvT = (u16*)(ws);                    //  6 MB: [3072][1024] bf16
    u16* WoutT = (u16*)(ws + 6291456);          //  2 MB: [1024][1024] bf16
    u16* xb    = (u16*)(ws + 8388608);          // 16 MB: [8192][1024] bf16
    u16* Qb    = (u16*)(ws + 25165824);         // 16 MB: [BH][T][D]
    u16* Kb    = (u16*)(ws + 41943040);         // 16 MB: [BH][T][D]
    u16* Vtb   = (u16*)(ws + 58720256);         // 16 MB: [BH][D][T]
    u16* Ab    = (u16*)(ws + 75497472);         // 16 MB: [B][T][C]

    castk<<<dim3(4096), 256, 0, stream>>>(x, xb);
    tkern<<<dim3(16 * 48), 256, 0, stream>>>(Wqkv, WqkvT, 1024, 3072);
    tkern<<<dim3(16 * 16), 256, 0, stream>>>(Wout, WoutT, 1024, 1024);
    gemm_k<0><<<dim3(64 * 24), 256, 0, stream>>>(xb, WqkvT, bqkv, Qb, Kb, Vtb, nullptr);
    flash_attn<<<dim3(16, 64), 128, 0, stream>>>(Qb, Kb, Vtb, Ab);
    gemm_k<1><<<dim3(64 * 8), 256, 0, stream>>>(Ab, WoutT, bout, nullptr, nullptr, nullptr, out);
}